// Round 10
// baseline (205.370 us; speedup 1.0000x reference)
//
#include <hip/hip_runtime.h>
#include <hip/hip_bf16.h>

// b=1, c=256, h=w=64 -> n=4096 pixels, 4 heads, hd=64, 32 groups x 8 ch.
// scale = hd^-0.5 = 0.125, folded into Wq (K0) and bq (K1 epilogue).
#define NPIX 4096
#define CCH  256
#define HD   64
#define GSIZE 32768   // 8 ch * 4096 pix per group

typedef __bf16 bf16x8 __attribute__((ext_vector_type(8)));
typedef __bf16 bf16x4 __attribute__((ext_vector_type(4)));
typedef float  f32x4  __attribute__((ext_vector_type(4)));

#define XPITCH 264   // X/F panel pitch (bf16) for K1/K3

// MFMA 16x16x32_bf16 layouts (verified m89/m91; used R2-R9):
//   A[m=lane&15][k=quad*8+j]; B[k=quad*8+j][n=lane&15]; C: row=quad*4+reg, col=lane&15

// ---------------------------------------------------------------------------
// K0: blocks 0..255: per-(group,1/8th) partial sums -> psum/pssq[256].
//     blocks 256..319: weight fp32->bf16 convert (Wq scaled 0.125).
// ---------------------------------------------------------------------------
__global__ __launch_bounds__(256) void stats_wconv(
    const float* __restrict__ X,
    const float* __restrict__ Wq, const float* __restrict__ Wk,
    const float* __restrict__ Wv, const float* __restrict__ Wp,
    float* __restrict__ psum, float* __restrict__ pssq, __bf16* __restrict__ Wb)
{
    const int bid = blockIdx.x, t = threadIdx.x;
    if (bid < 256) {
        const float* base = X + bid * 4096;   // (g = bid>>3, seg = bid&7)
        float sum = 0.f, ssq = 0.f;
        #pragma unroll
        for (int k = 0; k < 4; ++k) {
            float4 v = *(const float4*)(base + t * 4 + k * 1024);
            sum += v.x + v.y + v.z + v.w;
            ssq += v.x * v.x + v.y * v.y + v.z * v.z + v.w * v.w;
        }
        #pragma unroll
        for (int off = 1; off < 64; off <<= 1) {
            sum += __shfl_xor(sum, off);
            ssq += __shfl_xor(ssq, off);
        }
        __shared__ float red[2][4];
        const int wv = t >> 6;
        if ((t & 63) == 0) { red[0][wv] = sum; red[1][wv] = ssq; }
        __syncthreads();
        if (t == 0) {
            psum[bid] = red[0][0] + red[0][1] + red[0][2] + red[0][3];
            pssq[bid] = red[1][0] + red[1][1] + red[1][2] + red[1][3];
        }
    } else {
        const int j0 = (bid - 256) * 4096 + t * 16;
        const int m  = j0 >> 16;
        const float* W = (m == 0) ? Wq : (m == 1) ? Wk : (m == 2) ? Wv : Wp;
        const float sc = (m == 0) ? 0.125f : 1.f;
        const int off = j0 & 65535;
        #pragma unroll
        for (int k = 0; k < 4; ++k) {
            float4 v = *(const float4*)(W + off + k * 4);
            bf16x4 o;
            o[0] = (__bf16)(v.x * sc); o[1] = (__bf16)(v.y * sc);
            o[2] = (__bf16)(v.z * sc); o[3] = (__bf16)(v.w * sc);
            *(bf16x4*)(Wb + m * 65536 + off + k * 4) = o;
        }
    }
}

// ---------------------------------------------------------------------------
// K1: fused GroupNorm-apply + QKV MFMA GEMM. grid (64 pixblk, 6: z*2+och).
// (unchanged from R9)
// ---------------------------------------------------------------------------
__global__ __launch_bounds__(256) void gn_qkv(
    const float* __restrict__ X, const float* __restrict__ gamma,
    const float* __restrict__ beta,
    const float* __restrict__ psum, const float* __restrict__ pssq,
    const __bf16* __restrict__ Wb,
    const float* __restrict__ bq, const float* __restrict__ bk,
    const float* __restrict__ bv,
    __bf16* __restrict__ Qb, __bf16* __restrict__ Kb, __bf16* __restrict__ Vb)
{
    __shared__ __bf16 tile[64 * XPITCH];
    __shared__ float al[256], bl[256];

    const int t = threadIdx.x, lane = t & 63, wave = t >> 6;
    const int l16 = lane & 15, quad = lane >> 4;
    const int p0 = blockIdx.x * 64;
    const int z = blockIdx.y >> 1, och = blockIdx.y & 1;

    {
        const int g = t >> 3;
        float s = 0.f, q = 0.f;
        #pragma unroll
        for (int j = 0; j < 8; ++j) { s += psum[g * 8 + j]; q += pssq[g * 8 + j]; }
        const float mu  = s * (1.f / GSIZE);
        const float var = q * (1.f / GSIZE) - mu * mu;
        const float a = gamma[t] * rsqrtf(var + 1e-6f);
        al[t] = a;
        bl[t] = beta[t] - mu * a;
    }
    __syncthreads();

    #pragma unroll 4
    for (int i = 0; i < 16; ++i) {
        const int c4 = wave * 64 + i * 4;
        f32x4 a4 = *(const f32x4*)(al + c4);
        f32x4 b4 = *(const f32x4*)(bl + c4);
        bf16x4 pk;
        pk[0] = (__bf16)(X[(c4 + 0) * NPIX + p0 + lane] * a4[0] + b4[0]);
        pk[1] = (__bf16)(X[(c4 + 1) * NPIX + p0 + lane] * a4[1] + b4[1]);
        pk[2] = (__bf16)(X[(c4 + 2) * NPIX + p0 + lane] * a4[2] + b4[2]);
        pk[3] = (__bf16)(X[(c4 + 3) * NPIX + p0 + lane] * a4[3] + b4[3]);
        *(bf16x4*)(tile + lane * XPITCH + c4) = pk;
    }
    __syncthreads();

    const int pw = wave * 16;
    bf16x8 xf[8];
    #pragma unroll
    for (int kc = 0; kc < 8; ++kc)
        xf[kc] = *(const bf16x8*)(tile + (pw + l16) * XPITCH + kc * 32 + quad * 8);

    const __bf16* Wz = Wb + z * 65536;
    const float* bias = (z == 0) ? bq : (z == 1) ? bk : bv;

    if (z < 2) {
        const float qs = (z == 0) ? 0.125f : 1.f;
        __bf16* dst = (z == 0) ? Qb : Kb;
        #pragma unroll
        for (int grp = 0; grp < 2; ++grp) {
            f32x4 acc[4] = {};
            #pragma unroll
            for (int kc = 0; kc < 8; ++kc) {
                #pragma unroll
                for (int u = 0; u < 4; ++u) {
                    bf16x8 wf = *(const bf16x8*)(Wz + (och * 128 + (grp * 4 + u) * 16 + l16) * CCH + kc * 32 + quad * 8);
                    acc[u] = __builtin_amdgcn_mfma_f32_16x16x32_bf16(wf, xf[kc], acc[u], 0, 0, 0);
                }
            }
            #pragma unroll
            for (int u = 0; u < 4; ++u) {
                const int ot = och * 8 + grp * 4 + u;
                f32x4 bz = *(const f32x4*)(bias + och * 128 + (grp * 4 + u) * 16 + quad * 4);
                bf16x4 o;
                o[0] = (__bf16)(acc[u][0] + bz[0] * qs);
                o[1] = (__bf16)(acc[u][1] + bz[1] * qs);
                o[2] = (__bf16)(acc[u][2] + bz[2] * qs);
                o[3] = (__bf16)(acc[u][3] + bz[3] * qs);
                const int head = ot >> 2, dloc = (ot & 3) * 16 + quad * 4;
                *(bf16x4*)(dst + head * (NPIX * HD) + (p0 + pw + l16) * HD + dloc) = o;
            }
        }
    } else {
        #pragma unroll
        for (int grp = 0; grp < 2; ++grp) {
            f32x4 acc[4] = {};
            #pragma unroll
            for (int kc = 0; kc < 8; ++kc) {
                #pragma unroll
                for (int u = 0; u < 4; ++u) {
                    bf16x8 wf = *(const bf16x8*)(Wz + (och * 128 + (grp * 4 + u) * 16 + l16) * CCH + kc * 32 + quad * 8);
                    acc[u] = __builtin_amdgcn_mfma_f32_16x16x32_bf16(xf[kc], wf, acc[u], 0, 0, 0);
                }
            }
            #pragma unroll
            for (int u = 0; u < 4; ++u) {
                const int oc = och * 128 + (grp * 4 + u) * 16 + l16;
                const float bz = bias[oc];
                bf16x4 o;
                o[0] = (__bf16)(acc[u][0] + bz); o[1] = (__bf16)(acc[u][1] + bz);
                o[2] = (__bf16)(acc[u][2] + bz); o[3] = (__bf16)(acc[u][3] + bz);
                *(bf16x4*)(Vb + oc * NPIX + p0 + pw + quad * 4) = o;
            }
        }
    }
}

// ---------------------------------------------------------------------------
// K2: bf16 MFMA attention, LDS-staged (R9 dataflow) at 2 blocks/CU.
// Grid 512: (head 4) x (q-tile of 32 rows). Block = 4 waves (256 thr),
// __launch_bounds__(256,2) -> 2 co-resident blocks/CU = 2 waves/SIMD to
// overlap the serial ds_read->MFMA->exp->P-RAW chain (R9 was 1 wave/SIMD).
// Waves SHARE the 32 q-rows and SPLIT each 128-key tile 4 ways (32 keys/wave).
// K/V staged per tile into LDS (full-line coalesced), register-prefetch
// double-buffer, 1 barrier/tile. Max-free softmax; l via ones-MFMA;
// in-LDS 4-way key merge. Output bf16 flat F[pix*256 + head*64 + d].
// LDS 78848 B < 80K so two blocks fit in 160K.
// ---------------------------------------------------------------------------
#define KPITCH 68    // kt [key128][d64] pitch (bf16), 136 B rows
#define VPITCH 132   // vt [d64][key128] pitch (bf16), 264 B rows
#define PPIT   40    // pt per-wave [row32][key32] pitch (bf16), 80 B rows
#define KBUF   (128 * KPITCH)               // 8704 elems
#define VBUF   (64 * VPITCH)                // 8448 elems
#define OFF_V  (2 * KBUF * 2)               // 34816 B
#define OFF_P  (OFF_V + 2 * VBUF * 2)       // 68608 B
#define SMEMSZ (OFF_P + 4 * 32 * PPIT * 2)  // 78848 B

__global__ __launch_bounds__(256, 2) void attn_mfma(
    const __bf16* __restrict__ Qb, const __bf16* __restrict__ Kb,
    const __bf16* __restrict__ Vb, __bf16* __restrict__ Sb)
{
    __shared__ __align__(16) char smem[SMEMSZ];
    __bf16* ktls = (__bf16*)smem;
    __bf16* vtls = (__bf16*)(smem + OFF_V);
    __bf16* ptls = (__bf16*)(smem + OFF_P);
    float*  co   = (float*)smem;             // merge overlay (K region, 34816 B)
    float*  cl   = (float*)(smem + OFF_V);   // merge l overlay (V region, 512 B)

    const int t = threadIdx.x, lane = t & 63, wave = t >> 6;
    const int l16 = lane & 15, quad = lane >> 4;

    const int bid  = blockIdx.x;
    const int head = (bid & 7) >> 1;                   // XCD-pair pinning
    const int qt   = ((bid >> 3) << 1) | (bid & 1);    // 0..127
    const int p0   = qt * 32;

    const __bf16* Qh = Qb + head * (NPIX * HD);
    const __bf16* Kh = Kb + head * (NPIX * HD);
    const __bf16* Vh = Vb + head * (HD * NPIX);

    // Q B-frags for 32 shared rows: B[k=d][n=row16], rt = row-tile
    bf16x8 qf[2][2];
    #pragma unroll
    for (int rt = 0; rt < 2; ++rt) {
        const __bf16* qp = Qh + (p0 + rt * 16 + l16) * HD + quad * 8;
        qf[rt][0] = *(const bf16x8*)(qp);
        qf[rt][1] = *(const bf16x8*)(qp + 32);
    }

    bf16x8 ones;
    #pragma unroll
    for (int j = 0; j < 8; ++j) ones[j] = (__bf16)1.0f;

    f32x4 l_acc[2] = {};
    f32x4 o_acc[4][2] = {};   // [dt][rt]

    __bf16* ptw = ptls + wave * (32 * PPIT);

    // prefetch regs: 4 x 16B chunks each for K and V (full-line coalesced)
    bf16x8 kpre[4], vpre[4];
    #pragma unroll
    for (int i = 0; i < 4; ++i) {
        const int c = t + 256 * i;
        kpre[i] = *(const bf16x8*)(Kh + (c >> 3) * HD + (c & 7) * 8);
        vpre[i] = *(const bf16x8*)(Vh + (c >> 4) * NPIX + (c & 15) * 8);
    }

    for (int it = 0; it < 32; ++it) {
        const int b = it & 1;
        __bf16* ktb = ktls + b * KBUF;
        __bf16* vtb = vtls + b * VBUF;

        // write prefetched tile -> LDS buf b
        #pragma unroll
        for (int i = 0; i < 4; ++i) {
            const int c = t + 256 * i;
            *(bf16x8*)(ktb + (c >> 3) * KPITCH + (c & 7) * 8)  = kpre[i];
            *(bf16x8*)(vtb + (c >> 4) * VPITCH + (c & 15) * 8) = vpre[i];
        }
        __syncthreads();

        // issue next tile's global loads (consumed next iter)
        if (it < 31) {
            const int kb = (it + 1) * 128;
            #pragma unroll
            for (int i = 0; i < 4; ++i) {
                const int c = t + 256 * i;
                kpre[i] = *(const bf16x8*)(Kh + (kb + (c >> 3)) * HD + (c & 7) * 8);
                vpre[i] = *(const bf16x8*)(Vh + (c >> 4) * NPIX + kb + (c & 15) * 8);
            }
        }

        // ---- compute tile it from buf b; wave owns local keys [wave*32,+32) ----
        bf16x8 kf[2][2], vf[4];
        #pragma unroll
        for (int kt = 0; kt < 2; ++kt) {
            const __bf16* kp = ktb + (wave * 32 + kt * 16 + l16) * KPITCH + quad * 8;
            kf[kt][0] = *(const bf16x8*)(kp);
            kf[kt][1] = *(const bf16x8*)(kp + 32);
        }
        #pragma unroll
        for (int dt = 0; dt < 4; ++dt)
            vf[dt] = *(const bf16x8*)(vtb + (dt * 16 + l16) * VPITCH + wave * 32 + quad * 8);

        // S^T = K Q^T : C(key_local = kt*16+quad*4+r, row = rt*16+l16)
        f32x4 st[2][2] = {};
        #pragma unroll
        for (int kt = 0; kt < 2; ++kt)
            #pragma unroll
            for (int rt = 0; rt < 2; ++rt) {
                st[kt][rt] = __builtin_amdgcn_mfma_f32_16x16x32_bf16(kf[kt][0], qf[rt][0], st[kt][rt], 0, 0, 0);
                st[kt][rt] = __builtin_amdgcn_mfma_f32_16x16x32_bf16(kf[kt][1], qf[rt][1], st[kt][rt], 0, 0, 0);
            }

        // P = exp(S^T) -> per-wave P tile [row32][key_local 32]
        #pragma unroll
        for (int kt = 0; kt < 2; ++kt)
            #pragma unroll
            for (int rt = 0; rt < 2; ++rt) {
                bf16x4 p;
                p[0] = (__bf16)__expf(st[kt][rt][0]);
                p[1] = (__bf16)__expf(st[kt][rt][1]);
                p[2] = (__bf16)__expf(st[kt][rt][2]);
                p[3] = (__bf16)__expf(st[kt][rt][3]);
                *(bf16x4*)(ptw + (rt * 16 + l16) * PPIT + kt * 16 + quad * 4) = p;
            }

        // P B-frags (same-wave LDS RAW): B[k=key_local][n=row]
        bf16x8 bp[2];
        #pragma unroll
        for (int rt = 0; rt < 2; ++rt)
            bp[rt] = *(const bf16x8*)(ptw + (rt * 16 + l16) * PPIT + quad * 8);

        // l += rowsum(P) on the matrix pipe
        #pragma unroll
        for (int rt = 0; rt < 2; ++rt)
            l_acc[rt] = __builtin_amdgcn_mfma_f32_16x16x32_bf16(ones, bp[rt], l_acc[rt], 0, 0, 0);

        // O^T += V^T P^T : C(d = dt*16+quad*4+r, row = rt*16+l16)
        #pragma unroll
        for (int dt = 0; dt < 4; ++dt)
            #pragma unroll
            for (int rt = 0; rt < 2; ++rt)
                o_acc[dt][rt] = __builtin_amdgcn_mfma_f32_16x16x32_bf16(vf[dt], bp[rt], o_acc[dt][rt], 0, 0, 0);
        // no trailing barrier: next iter writes buf b^1 while stragglers read b
    }

    // ---- in-LDS 4-way key merge ----
    __syncthreads();   // everyone done with K/V/P LDS before overlay

    #pragma unroll
    for (int dt = 0; dt < 4; ++dt)
        #pragma unroll
        for (int rt = 0; rt < 2; ++rt)
            *(f32x4*)(co + wave * 2176 + (rt * 16 + l16) * 68 + dt * 16 + quad * 4) = o_acc[dt][rt];
    if (quad == 0) {
        #pragma unroll
        for (int rt = 0; rt < 2; ++rt)
            cl[wave * 32 + rt * 16 + l16] = l_acc[rt][0];
    }
    __syncthreads();

    {
        const int row = t >> 3, dg = (t & 7) * 8;
        const float l = cl[row] + cl[32 + row] + cl[64 + row] + cl[96 + row];
        const float inv = 1.f / l;
        f32x4 s0 = {}, s1 = {};
        #pragma unroll
        for (int w = 0; w < 4; ++w) {
            s0 += *(const f32x4*)(co + w * 2176 + row * 68 + dg);
            s1 += *(const f32x4*)(co + w * 2176 + row * 68 + dg + 4);
        }
        bf16x8 o;
        o[0] = (__bf16)(s0[0] * inv); o[1] = (__bf16)(s0[1] * inv);
        o[2] = (__bf16)(s0[2] * inv); o[3] = (__bf16)(s0[3] * inv);
        o[4] = (__bf16)(s1[0] * inv); o[5] = (__bf16)(s1[1] * inv);
        o[6] = (__bf16)(s1[2] * inv); o[7] = (__bf16)(s1[3] * inv);
        *(bf16x8*)(Sb + (p0 + row) * CCH + head * HD + dg) = o;
    }
}

// ---------------------------------------------------------------------------
// K3: proj bf16 MFMA GEMM + bias + residual, fp32 out [c][pix].
// (unchanged from R9)
// ---------------------------------------------------------------------------
__global__ __launch_bounds__(256) void gemm_proj(
    const __bf16* __restrict__ Sb, const __bf16* __restrict__ Wpb,
    const float* __restrict__ bias, const float* __restrict__ X,
    float* __restrict__ Out)
{
    __shared__ __bf16 Bs[32 * XPITCH];

    const int t = threadIdx.x, lane = t & 63, wave = t >> 6;
    const int l16 = lane & 15, quad = lane >> 4;
    const int p0  = blockIdx.x * 32;
    const int och = blockIdx.y;

    #pragma unroll
    for (int pg = 0; pg < 4; ++pg) {
        bf16x8 v = *(const bf16x8*)(Sb + t * NPIX + p0 + pg * 8);
        #pragma unroll
        for (int j = 0; j < 8; ++j)
            Bs[(pg * 8 + j) * XPITCH + t] = v[j];
    }
    __syncthreads();

    const int pixset = wave & 1, ocset = wave >> 1;
    bf16x8 af[8];
    #pragma unroll
    for (int kc = 0; kc < 8; ++kc)
        af[kc] = *(const bf16x8*)(Bs + (pixset * 16 + l16) * XPITCH + kc * 32 + quad * 8);

    #pragma unroll
    for (int u = 0; u < 4; ++u) {
        f32x4 acc = {};
        const int oc_t = och * 128 + ocset * 64 + u * 16;
        #pragma unroll
        for (int kc = 0; kc < 8; ++kc) {
            bf16x8 wf = *(const bf16x8*)(Wpb + (oc_t + l16) * CCH + kc * 32 + quad * 8);
            acc = __builtin_amdgcn_mfma_f32_16x16x32_bf16(af[kc], wf, acc, 0, 0, 0);
        }
        const int oc  = oc_t + l16;
        const int pix = p0 + pixset * 16 + quad * 4;
        const float bz = bias[oc];
        f32x4 r4 = *(const f32x4*)(X + oc * NPIX + pix);
        f32x4 y;
        y[0] = acc[0] + bz + r4[0];
        y[1] = acc[1] + bz + r4[1];
        y[2] = acc[2] + bz + r4[2];
        y[3] = acc[3] + bz + r4[3];
        *(f32x4*)(Out + oc * NPIX + pix) = y;
    }
}

// ---------------------------------------------------------------------------
extern "C" void kernel_launch(void* const* d_in, const int* in_sizes, int n_in,
                              void* d_out, int out_size, void* d_ws, size_t ws_size,
                              hipStream_t stream)
{
    const float* x     = (const float*)d_in[0];
    const float* gamma = (const float*)d_in[1];
    const float* beta  = (const float*)d_in[2];
    const float* Wq    = (const float*)d_in[3];
    const float* bq    = (const float*)d_in[4];
    const float* Wk    = (const float*)d_in[5];
    const float* bk    = (const float*)d_in[6];
    const float* Wv    = (const float*)d_in[7];
    const float* bv    = (const float*)d_in[8];
    const float* Wp    = (const float*)d_in[9];
    const float* bp    = (const float*)d_in[10];
    float* out = (float*)d_out;

    char* ws = (char*)d_ws;
    float*  psum = (float*)(ws);                // 1KB stats partial sums
    float*  pssq = (float*)(ws + 1024);         // 1KB
    __bf16* Wb   = (__bf16*)(ws + 65536);       // 512KB bf16 4x[256][256]
    __bf16* Qb   = (__bf16*)(ws + (1 << 20));   // 2MB bf16 [head][pix][64]
    __bf16* Kb   = (__bf16*)(ws + (3 << 20));   // 2MB bf16 [head][pix][64]
    __bf16* Vb   = (__bf16*)(ws + (5 << 20));   // 2MB bf16 [c][pix]
    __bf16* Sb   = (__bf16*)(ws + (7 << 20));   // 2MB bf16 flat F

    stats_wconv<<<320, 256, 0, stream>>>(x, Wq, Wk, Wv, Wp, psum, pssq, Wb);

    dim3 gq(64, 6);
    gn_qkv<<<gq, 256, 0, stream>>>(x, gamma, beta, psum, pssq, Wb,
                                   bq, bk, bv, Qb, Kb, Vb);

    attn_mfma<<<512, 256, 0, stream>>>(Qb, Kb, Vb, Sb);

    dim3 gp(128, 2);
    gemm_proj<<<gp, 256, 0, stream>>>(Sb, Wb + 3 * 65536, bp, x, out);
}

// Round 11
// 172.872 us; speedup vs baseline: 1.1880x; 1.1880x over previous
//
#include <hip/hip_runtime.h>
#include <hip/hip_bf16.h>

// b=1, c=256, h=w=64 -> n=4096 pixels, 4 heads, hd=64, 32 groups x 8 ch.
// scale = hd^-0.5 = 0.125, folded into Wq (K0) and bq (K1 epilogue).
#define NPIX 4096
#define CCH  256
#define HD   64
#define GSIZE 32768   // 8 ch * 4096 pix per group

typedef __bf16 bf16x8 __attribute__((ext_vector_type(8)));
typedef __bf16 bf16x4 __attribute__((ext_vector_type(4)));
typedef float  f32x4  __attribute__((ext_vector_type(4)));

#define XPITCH 264   // X/F panel pitch (bf16) for K1/K3

// MFMA 16x16x32_bf16 layouts (verified m89/m91; used R2-R10):
//   A[m=lane&15][k=quad*8+j]; B[k=quad*8+j][n=lane&15]; C: row=quad*4+reg, col=lane&15

// ---------------------------------------------------------------------------
// K0: blocks 0..255: per-(group,1/8th) partial sums -> psum/pssq[256].
//     blocks 256..319: weight fp32->bf16 convert (Wq scaled 0.125).
// ---------------------------------------------------------------------------
__global__ __launch_bounds__(256) void stats_wconv(
    const float* __restrict__ X,
    const float* __restrict__ Wq, const float* __restrict__ Wk,
    const float* __restrict__ Wv, const float* __restrict__ Wp,
    float* __restrict__ psum, float* __restrict__ pssq, __bf16* __restrict__ Wb)
{
    const int bid = blockIdx.x, t = threadIdx.x;
    if (bid < 256) {
        const float* base = X + bid * 4096;   // (g = bid>>3, seg = bid&7)
        float sum = 0.f, ssq = 0.f;
        #pragma unroll
        for (int k = 0; k < 4; ++k) {
            float4 v = *(const float4*)(base + t * 4 + k * 1024);
            sum += v.x + v.y + v.z + v.w;
            ssq += v.x * v.x + v.y * v.y + v.z * v.z + v.w * v.w;
        }
        #pragma unroll
        for (int off = 1; off < 64; off <<= 1) {
            sum += __shfl_xor(sum, off);
            ssq += __shfl_xor(ssq, off);
        }
        __shared__ float red[2][4];
        const int wv = t >> 6;
        if ((t & 63) == 0) { red[0][wv] = sum; red[1][wv] = ssq; }
        __syncthreads();
        if (t == 0) {
            psum[bid] = red[0][0] + red[0][1] + red[0][2] + red[0][3];
            pssq[bid] = red[1][0] + red[1][1] + red[1][2] + red[1][3];
        }
    } else {
        const int j0 = (bid - 256) * 4096 + t * 16;
        const int m  = j0 >> 16;
        const float* W = (m == 0) ? Wq : (m == 1) ? Wk : (m == 2) ? Wv : Wp;
        const float sc = (m == 0) ? 0.125f : 1.f;
        const int off = j0 & 65535;
        #pragma unroll
        for (int k = 0; k < 4; ++k) {
            float4 v = *(const float4*)(W + off + k * 4);
            bf16x4 o;
            o[0] = (__bf16)(v.x * sc); o[1] = (__bf16)(v.y * sc);
            o[2] = (__bf16)(v.z * sc); o[3] = (__bf16)(v.w * sc);
            *(bf16x4*)(Wb + m * 65536 + off + k * 4) = o;
        }
    }
}

// ---------------------------------------------------------------------------
// K1: fused GroupNorm-apply + QKV MFMA GEMM. grid (64 pixblk, 6: z*2+och).
// (unchanged from R9)
// ---------------------------------------------------------------------------
__global__ __launch_bounds__(256) void gn_qkv(
    const float* __restrict__ X, const float* __restrict__ gamma,
    const float* __restrict__ beta,
    const float* __restrict__ psum, const float* __restrict__ pssq,
    const __bf16* __restrict__ Wb,
    const float* __restrict__ bq, const float* __restrict__ bk,
    const float* __restrict__ bv,
    __bf16* __restrict__ Qb, __bf16* __restrict__ Kb, __bf16* __restrict__ Vb)
{
    __shared__ __bf16 tile[64 * XPITCH];
    __shared__ float al[256], bl[256];

    const int t = threadIdx.x, lane = t & 63, wave = t >> 6;
    const int l16 = lane & 15, quad = lane >> 4;
    const int p0 = blockIdx.x * 64;
    const int z = blockIdx.y >> 1, och = blockIdx.y & 1;

    {
        const int g = t >> 3;
        float s = 0.f, q = 0.f;
        #pragma unroll
        for (int j = 0; j < 8; ++j) { s += psum[g * 8 + j]; q += pssq[g * 8 + j]; }
        const float mu  = s * (1.f / GSIZE);
        const float var = q * (1.f / GSIZE) - mu * mu;
        const float a = gamma[t] * rsqrtf(var + 1e-6f);
        al[t] = a;
        bl[t] = beta[t] - mu * a;
    }
    __syncthreads();

    #pragma unroll 4
    for (int i = 0; i < 16; ++i) {
        const int c4 = wave * 64 + i * 4;
        f32x4 a4 = *(const f32x4*)(al + c4);
        f32x4 b4 = *(const f32x4*)(bl + c4);
        bf16x4 pk;
        pk[0] = (__bf16)(X[(c4 + 0) * NPIX + p0 + lane] * a4[0] + b4[0]);
        pk[1] = (__bf16)(X[(c4 + 1) * NPIX + p0 + lane] * a4[1] + b4[1]);
        pk[2] = (__bf16)(X[(c4 + 2) * NPIX + p0 + lane] * a4[2] + b4[2]);
        pk[3] = (__bf16)(X[(c4 + 3) * NPIX + p0 + lane] * a4[3] + b4[3]);
        *(bf16x4*)(tile + lane * XPITCH + c4) = pk;
    }
    __syncthreads();

    const int pw = wave * 16;
    bf16x8 xf[8];
    #pragma unroll
    for (int kc = 0; kc < 8; ++kc)
        xf[kc] = *(const bf16x8*)(tile + (pw + l16) * XPITCH + kc * 32 + quad * 8);

    const __bf16* Wz = Wb + z * 65536;
    const float* bias = (z == 0) ? bq : (z == 1) ? bk : bv;

    if (z < 2) {
        const float qs = (z == 0) ? 0.125f : 1.f;
        __bf16* dst = (z == 0) ? Qb : Kb;
        #pragma unroll
        for (int grp = 0; grp < 2; ++grp) {
            f32x4 acc[4] = {};
            #pragma unroll
            for (int kc = 0; kc < 8; ++kc) {
                #pragma unroll
                for (int u = 0; u < 4; ++u) {
                    bf16x8 wf = *(const bf16x8*)(Wz + (och * 128 + (grp * 4 + u) * 16 + l16) * CCH + kc * 32 + quad * 8);
                    acc[u] = __builtin_amdgcn_mfma_f32_16x16x32_bf16(wf, xf[kc], acc[u], 0, 0, 0);
                }
            }
            #pragma unroll
            for (int u = 0; u < 4; ++u) {
                const int ot = och * 8 + grp * 4 + u;
                f32x4 bz = *(const f32x4*)(bias + och * 128 + (grp * 4 + u) * 16 + quad * 4);
                bf16x4 o;
                o[0] = (__bf16)(acc[u][0] + bz[0] * qs);
                o[1] = (__bf16)(acc[u][1] + bz[1] * qs);
                o[2] = (__bf16)(acc[u][2] + bz[2] * qs);
                o[3] = (__bf16)(acc[u][3] + bz[3] * qs);
                const int head = ot >> 2, dloc = (ot & 3) * 16 + quad * 4;
                *(bf16x4*)(dst + head * (NPIX * HD) + (p0 + pw + l16) * HD + dloc) = o;
            }
        }
    } else {
        #pragma unroll
        for (int grp = 0; grp < 2; ++grp) {
            f32x4 acc[4] = {};
            #pragma unroll
            for (int kc = 0; kc < 8; ++kc) {
                #pragma unroll
                for (int u = 0; u < 4; ++u) {
                    bf16x8 wf = *(const bf16x8*)(Wz + (och * 128 + (grp * 4 + u) * 16 + l16) * CCH + kc * 32 + quad * 8);
                    acc[u] = __builtin_amdgcn_mfma_f32_16x16x32_bf16(xf[kc], wf, acc[u], 0, 0, 0);
                }
            }
            #pragma unroll
            for (int u = 0; u < 4; ++u) {
                const int oc = och * 128 + (grp * 4 + u) * 16 + l16;
                const float bz = bias[oc];
                bf16x4 o;
                o[0] = (__bf16)(acc[u][0] + bz); o[1] = (__bf16)(acc[u][1] + bz);
                o[2] = (__bf16)(acc[u][2] + bz); o[3] = (__bf16)(acc[u][3] + bz);
                *(bf16x4*)(Vb + oc * NPIX + p0 + pw + quad * 4) = o;
            }
        }
    }
}

// ---------------------------------------------------------------------------
// K2: bf16 MFMA attention = R9 dataflow (grid 256, 64-row q-tile, 4 waves,
// waves split each 128-key tile 4 ways) but SINGLE-buffered K/V LDS so the
// block fits 2x/CU (LDS 70656 B, VGPR<=256, __launch_bounds__(256,2)).
// Register-prefetch keeps global latency hidden; 2 barriers/iter; total
// staging work identical to R9 (the R10 mistake doubled it).
// Max-free softmax; l via ones-MFMA; in-LDS 4-way key merge.
// Output bf16 flat F[pix*256 + head*64 + d].
// ---------------------------------------------------------------------------
#define KPITCH 68    // kt [key128][d64] pitch, 136 B rows
#define VPITCH 132   // vt [d64][key128] pitch, 264 B rows
#define PPIT   40    // pt per-wave [row64][key32] pitch, 80 B rows
#define OFF_V  17408                        // K: 128*68*2
#define OFF_P  (OFF_V + 16896)              // V: 64*132*2 -> 34304
#define SMEMSZ 70656                        // merge overlay: co 69632 + cl 1024

__global__ __launch_bounds__(256, 2) void attn_mfma(
    const __bf16* __restrict__ Qb, const __bf16* __restrict__ Kb,
    const __bf16* __restrict__ Vb, __bf16* __restrict__ Sb)
{
    __shared__ __align__(16) char smem[SMEMSZ];
    __bf16* ktb  = (__bf16*)smem;
    __bf16* vtb  = (__bf16*)(smem + OFF_V);
    __bf16* ptls = (__bf16*)(smem + OFF_P);
    float*  co   = (float*)smem;                 // merge overlay (after loop)
    float*  cl   = (float*)(smem + 69632);

    const int t = threadIdx.x, lane = t & 63, wave = t >> 6;
    const int l16 = lane & 15, quad = lane >> 4;

    const int bid  = blockIdx.x;
    const int head = (bid & 7) >> 1;                   // XCD-pair pinning
    const int qt   = ((bid >> 3) << 1) | (bid & 1);    // 0..63
    const int p0   = qt * 64;

    const __bf16* Qh = Qb + head * (NPIX * HD);
    const __bf16* Kh = Kb + head * (NPIX * HD);
    const __bf16* Vh = Vb + head * (HD * NPIX);

    // Q B-frags for 64 shared rows: B[k=d][n=row16], rt = row-tile
    bf16x8 qf[4][2];
    #pragma unroll
    for (int rt = 0; rt < 4; ++rt) {
        const __bf16* qp = Qh + (p0 + rt * 16 + l16) * HD + quad * 8;
        qf[rt][0] = *(const bf16x8*)(qp);
        qf[rt][1] = *(const bf16x8*)(qp + 32);
    }

    bf16x8 ones;
    #pragma unroll
    for (int j = 0; j < 8; ++j) ones[j] = (__bf16)1.0f;

    f32x4 l_acc[4] = {};
    f32x4 o_acc[4][4] = {};   // [dt][rt]

    __bf16* ptw = ptls + wave * (64 * PPIT);

    // prologue: tile 0 -> regs -> LDS; tile 1 -> regs
    bf16x8 kpre[4], vpre[4];
    #pragma unroll
    for (int i = 0; i < 4; ++i) {
        const int c = t + 256 * i;
        kpre[i] = *(const bf16x8*)(Kh + (c >> 3) * HD + (c & 7) * 8);
        vpre[i] = *(const bf16x8*)(Vh + (c >> 4) * NPIX + (c & 15) * 8);
    }
    #pragma unroll
    for (int i = 0; i < 4; ++i) {
        const int c = t + 256 * i;
        *(bf16x8*)(ktb + (c >> 3) * KPITCH + (c & 7) * 8)  = kpre[i];
        *(bf16x8*)(vtb + (c >> 4) * VPITCH + (c & 15) * 8) = vpre[i];
    }
    #pragma unroll
    for (int i = 0; i < 4; ++i) {
        const int c = t + 256 * i;
        kpre[i] = *(const bf16x8*)(Kh + (128 + (c >> 3)) * HD + (c & 7) * 8);
        vpre[i] = *(const bf16x8*)(Vh + (c >> 4) * NPIX + 128 + (c & 15) * 8);
    }
    __syncthreads();

    for (int it = 0; it < 32; ++it) {
        // ---- read this tile's frags from LDS (wave owns keys [wave*32,+32)) ----
        bf16x8 kf[2][2], vf[4];
        #pragma unroll
        for (int kt = 0; kt < 2; ++kt) {
            const __bf16* kp = ktb + (wave * 32 + kt * 16 + l16) * KPITCH + quad * 8;
            kf[kt][0] = *(const bf16x8*)(kp);
            kf[kt][1] = *(const bf16x8*)(kp + 32);
        }
        #pragma unroll
        for (int dt = 0; dt < 4; ++dt)
            vf[dt] = *(const bf16x8*)(vtb + (dt * 16 + l16) * VPITCH + wave * 32 + quad * 8);

        __syncthreads();   // all waves done reading before overwrite

        // ---- write prefetched tile it+1 -> LDS; issue loads for it+2 ----
        if (it < 31) {
            #pragma unroll
            for (int i = 0; i < 4; ++i) {
                const int c = t + 256 * i;
                *(bf16x8*)(ktb + (c >> 3) * KPITCH + (c & 7) * 8)  = kpre[i];
                *(bf16x8*)(vtb + (c >> 4) * VPITCH + (c & 15) * 8) = vpre[i];
            }
            if (it < 30) {
                const int kb = (it + 2) * 128;
                #pragma unroll
                for (int i = 0; i < 4; ++i) {
                    const int c = t + 256 * i;
                    kpre[i] = *(const bf16x8*)(Kh + (kb + (c >> 3)) * HD + (c & 7) * 8);
                    vpre[i] = *(const bf16x8*)(Vh + (c >> 4) * NPIX + kb + (c & 15) * 8);
                }
            }
        }

        // ---- S^T = K Q^T : C(key_local = kt*16+quad*4+r, row = rt*16+l16) ----
        f32x4 st[2][4] = {};
        #pragma unroll
        for (int kt = 0; kt < 2; ++kt)
            #pragma unroll
            for (int rt = 0; rt < 4; ++rt) {
                st[kt][rt] = __builtin_amdgcn_mfma_f32_16x16x32_bf16(kf[kt][0], qf[rt][0], st[kt][rt], 0, 0, 0);
                st[kt][rt] = __builtin_amdgcn_mfma_f32_16x16x32_bf16(kf[kt][1], qf[rt][1], st[kt][rt], 0, 0, 0);
            }

        // ---- P = exp(S^T) -> per-wave P tile [row64][key_local 32] ----
        #pragma unroll
        for (int kt = 0; kt < 2; ++kt)
            #pragma unroll
            for (int rt = 0; rt < 4; ++rt) {
                bf16x4 p;
                p[0] = (__bf16)__expf(st[kt][rt][0]);
                p[1] = (__bf16)__expf(st[kt][rt][1]);
                p[2] = (__bf16)__expf(st[kt][rt][2]);
                p[3] = (__bf16)__expf(st[kt][rt][3]);
                *(bf16x4*)(ptw + (rt * 16 + l16) * PPIT + kt * 16 + quad * 4) = p;
            }

        // ---- P B-frags (same-wave LDS RAW): B[k=key_local][n=row] ----
        bf16x8 bp[4];
        #pragma unroll
        for (int rt = 0; rt < 4; ++rt)
            bp[rt] = *(const bf16x8*)(ptw + (rt * 16 + l16) * PPIT + quad * 8);

        // ---- l += rowsum(P) on the matrix pipe ----
        #pragma unroll
        for (int rt = 0; rt < 4; ++rt)
            l_acc[rt] = __builtin_amdgcn_mfma_f32_16x16x32_bf16(ones, bp[rt], l_acc[rt], 0, 0, 0);

        // ---- O^T += V^T P^T : C(d = dt*16+quad*4+r, row = rt*16+l16) ----
        #pragma unroll
        for (int dt = 0; dt < 4; ++dt)
            #pragma unroll
            for (int rt = 0; rt < 4; ++rt)
                o_acc[dt][rt] = __builtin_amdgcn_mfma_f32_16x16x32_bf16(vf[dt], bp[rt], o_acc[dt][rt], 0, 0, 0);

        __syncthreads();   // staging writes visible before next iter's frag reads
    }

    // ---- in-LDS 4-way key merge (overlay; all P/K/V use is done) ----
    #pragma unroll
    for (int dt = 0; dt < 4; ++dt)
        #pragma unroll
        for (int rt = 0; rt < 4; ++rt)
            *(f32x4*)(co + wave * 4352 + (rt * 16 + l16) * 68 + dt * 16 + quad * 4) = o_acc[dt][rt];
    if (quad == 0) {
        #pragma unroll
        for (int rt = 0; rt < 4; ++rt)
            cl[wave * 64 + rt * 16 + l16] = l_acc[rt][0];
    }
    __syncthreads();

    {
        const int row = t >> 2, dc = (t & 3) * 16;
        const float l = cl[row] + cl[64 + row] + cl[128 + row] + cl[192 + row];
        const float inv = 1.f / l;
        f32x4 s[4];
        #pragma unroll
        for (int j = 0; j < 4; ++j) {
            s[j] = f32x4{0.f, 0.f, 0.f, 0.f};
            #pragma unroll
            for (int w = 0; w < 4; ++w)
                s[j] += *(const f32x4*)(co + w * 4352 + row * 68 + dc + j * 4);
        }
        bf16x8 o1, o2;
        #pragma unroll
        for (int j = 0; j < 4; ++j) {
            o1[j]     = (__bf16)(s[0][j] * inv);
            o1[j + 4] = (__bf16)(s[1][j] * inv);
            o2[j]     = (__bf16)(s[2][j] * inv);
            o2[j + 4] = (__bf16)(s[3][j] * inv);
        }
        __bf16* dst = Sb + (p0 + row) * CCH + head * HD + dc;
        *(bf16x8*)(dst)     = o1;
        *(bf16x8*)(dst + 8) = o2;
    }
}

// ---------------------------------------------------------------------------
// K3: proj bf16 MFMA GEMM + bias + residual, fp32 out [c][pix].
// (unchanged from R9)
// ---------------------------------------------------------------------------
__global__ __launch_bounds__(256) void gemm_proj(
    const __bf16* __restrict__ Sb, const __bf16* __restrict__ Wpb,
    const float* __restrict__ bias, const float* __restrict__ X,
    float* __restrict__ Out)
{
    __shared__ __bf16 Bs[32 * XPITCH];

    const int t = threadIdx.x, lane = t & 63, wave = t >> 6;
    const int l16 = lane & 15, quad = lane >> 4;
    const int p0  = blockIdx.x * 32;
    const int och = blockIdx.y;

    #pragma unroll
    for (int pg = 0; pg < 4; ++pg) {
        bf16x8 v = *(const bf16x8*)(Sb + t * NPIX + p0 + pg * 8);
        #pragma unroll
        for (int j = 0; j < 8; ++j)
            Bs[(pg * 8 + j) * XPITCH + t] = v[j];
    }
    __syncthreads();

    const int pixset = wave & 1, ocset = wave >> 1;
    bf16x8 af[8];
    #pragma unroll
    for (int kc = 0; kc < 8; ++kc)
        af[kc] = *(const bf16x8*)(Bs + (pixset * 16 + l16) * XPITCH + kc * 32 + quad * 8);

    #pragma unroll
    for (int u = 0; u < 4; ++u) {
        f32x4 acc = {};
        const int oc_t = och * 128 + ocset * 64 + u * 16;
        #pragma unroll
        for (int kc = 0; kc < 8; ++kc) {
            bf16x8 wf = *(const bf16x8*)(Wpb + (oc_t + l16) * CCH + kc * 32 + quad * 8);
            acc = __builtin_amdgcn_mfma_f32_16x16x32_bf16(af[kc], wf, acc, 0, 0, 0);
        }
        const int oc  = oc_t + l16;
        const int pix = p0 + pixset * 16 + quad * 4;
        const float bz = bias[oc];
        f32x4 r4 = *(const f32x4*)(X + oc * NPIX + pix);
        f32x4 y;
        y[0] = acc[0] + bz + r4[0];
        y[1] = acc[1] + bz + r4[1];
        y[2] = acc[2] + bz + r4[2];
        y[3] = acc[3] + bz + r4[3];
        *(f32x4*)(Out + oc * NPIX + pix) = y;
    }
}

// ---------------------------------------------------------------------------
extern "C" void kernel_launch(void* const* d_in, const int* in_sizes, int n_in,
                              void* d_out, int out_size, void* d_ws, size_t ws_size,
                              hipStream_t stream)
{
    const float* x     = (const float*)d_in[0];
    const float* gamma = (const float*)d_in[1];
    const float* beta  = (const float*)d_in[2];
    const float* Wq    = (const float*)d_in[3];
    const float* bq    = (const float*)d_in[4];
    const float* Wk    = (const float*)d_in[5];
    const float* bk    = (const float*)d_in[6];
    const float* Wv    = (const float*)d_in[7];
    const float* bv    = (const float*)d_in[8];
    const float* Wp    = (const float*)d_in[9];
    const float* bp    = (const float*)d_in[10];
    float* out = (float*)d_out;

    char* ws = (char*)d_ws;
    float*  psum = (float*)(ws);                // 1KB stats partial sums
    float*  pssq = (float*)(ws + 1024);         // 1KB
    __bf16* Wb   = (__bf16*)(ws + 65536);       // 512KB bf16 4x[256][256]
    __bf16* Qb   = (__bf16*)(ws + (1 << 20));   // 2MB bf16 [head][pix][64]
    __bf16* Kb   = (__bf16*)(ws + (3 << 20));   // 2MB bf16 [head][pix][64]
    __bf16* Vb   = (__bf16*)(ws + (5 << 20));   // 2MB bf16 [c][pix]
    __bf16* Sb   = (__bf16*)(ws + (7 << 20));   // 2MB bf16 flat F

    stats_wconv<<<320, 256, 0, stream>>>(x, Wq, Wk, Wv, Wp, psum, pssq, Wb);

    dim3 gq(64, 6);
    gn_qkv<<<gq, 256, 0, stream>>>(x, gamma, beta, psum, pssq, Wb,
                                   bq, bk, bv, Qb, Kb, Vb);

    attn_mfma<<<256, 256, 0, stream>>>(Qb, Kb, Vb, Sb);

    dim3 gp(128, 2);
    gemm_proj<<<gp, 256, 0, stream>>>(Sb, Wb + 3 * 65536, bp, x, out);
}